// Round 3
// baseline (142.510 us; speedup 1.0000x reference)
//
#include <hip/hip_runtime.h>

#define TPB 256
#define F4_PER_THREAD 8
#define F4_PER_BLOCK (TPB * F4_PER_THREAD)  // 2048 float4 = 32 KB per block

// Single-pass fused kernel. Grid: (chunks_per_plane, B*N).
// Wave 0 of each block computes its plane's 6x6 analytic blurred patch
// (mask^2 * sum_{4 corners} coef * gk) into LDS, then all threads stream
// zeros (fast path: two compares in linear-float4 space) or patch values.
__global__ __launch_bounds__(TPB) void fused_k(const float* __restrict__ Xg,
                                               const float* __restrict__ kp,
                                               const float* __restrict__ gk,
                                               const int* __restrict__ pH,
                                               const int* __restrict__ pW,
                                               float4* __restrict__ out4,
                                               int N) {
    const int H = *pH, W = *pW;
    const int W4 = W >> 2;
    const int HW4 = H * W4;
    const int bn = blockIdx.y;
    const int t  = threadIdx.x;

    __shared__ float s_pv[36];
    __shared__ int s_lo, s_hi, s_r0, s_c0;

    if (t < 64) {
        const int b = bn / N;
        const float* xrow = Xg + (size_t)bn * N;     // one-hot (or zero) row
        const float* kpb  = kp + (size_t)b * N * 2;  // keypoints for this batch

        float m = 0.f, sx = 0.f, sy = 0.f;
        for (int j = t; j < N; j += 64) {
            float w = xrow[j];
            m  += w;
            sx = fmaf(w, kpb[2 * j],     sx);
            sy = fmaf(w, kpb[2 * j + 1], sy);
        }
        #pragma unroll
        for (int off = 32; off > 0; off >>= 1) {
            m  += __shfl_xor(m,  off, 64);
            sx += __shfl_xor(sx, off, 64);
            sy += __shfl_xor(sy, off, 64);
        }

        if (m == 0.f) {
            if (t == 0) { s_lo = 0; s_hi = 0; s_r0 = 0; s_c0 = 0; }
        } else {
            const float xf = sx * 0.0625f - 0.5f;   // / IM_FE_RATIO - 0.5
            const float yf = sy * 0.0625f - 0.5f;
            const float maxx = (float)(W - 1), maxy = (float)(H - 1);

            const float x0 = fminf(fmaxf(floorf(xf), 0.f), maxx);
            const float x1 = fminf(fmaxf(ceilf (xf), 0.f), maxx);
            const float y0 = fminf(fmaxf(floorf(yf), 0.f), maxy);
            const float y1 = fminf(fmaxf(ceilf (yf), 0.f), maxy);

            const float upx = xf - x0, lwx = 1.f - upx;
            const float upy = yf - y0, lwy = 1.f - upy;

            const int   xc[2] = { (int)x0, (int)x1 };
            const int   yc[2] = { (int)y0, (int)y1 };
            const float wx[2] = { lwx, upx };
            const float wy[2] = { lwy, upy };

            const int r0 = yc[0] - 2, c0 = xc[0] - 2;
            if (t == 0) {
                s_r0 = r0; s_c0 = c0;
                s_lo = max(r0, 0) * W4;          // patch row band in float4 units
                s_hi = min(r0 + 6, H) * W4;
            }
            if (t < 36) {
                const int rr = r0 + t / 6;
                const int cc = c0 + t % 6;
                float v = 0.f;
                #pragma unroll
                for (int cy = 0; cy < 2; ++cy) {
                    const int dy = yc[cy] - rr + 2;
                    if (dy < 0 || dy > 4) continue;
                    #pragma unroll
                    for (int cx = 0; cx < 2; ++cx) {
                        const int dx = xc[cx] - cc + 2;
                        if (dx < 0 || dx > 4) continue;
                        v = fmaf(wy[cy] * wx[cx], gk[dy * 5 + dx], v);
                    }
                }
                s_pv[t] = m * m * v;
            }
        }
    }
    __syncthreads();

    const int lo = s_lo, hi = s_hi, r0 = s_r0, c0 = s_c0;
    const size_t planeBase = (size_t)bn * (size_t)HW4;
    const int base = blockIdx.x * F4_PER_BLOCK + t;
    const float4 z = make_float4(0.f, 0.f, 0.f, 0.f);

    #pragma unroll
    for (int k = 0; k < F4_PER_THREAD; ++k) {
        const int L = base + k * TPB;           // float4 index within the plane
        if (L >= HW4) break;
        if (L < lo || L >= hi) {
            out4[planeBase + L] = z;            // fast path: outside patch rows
        } else {
            const int row = L / W4;             // rare path (~2.3% of float4s)
            const int colBase = (L - row * W4) << 2;
            float4 v;
            float* vp = (float*)&v;
            const int dr = row - r0;            // in [0,5] by construction
            #pragma unroll
            for (int j = 0; j < 4; ++j) {
                const int dc = colBase + j - c0;
                vp[j] = ((unsigned)dc <= 5u) ? s_pv[dr * 6 + dc] : 0.f;
            }
            out4[planeBase + L] = v;
        }
    }
}

extern "C" void kernel_launch(void* const* d_in, const int* in_sizes, int n_in,
                              void* d_out, int out_size, void* d_ws, size_t ws_size,
                              hipStream_t stream) {
    const float* Xg = (const float*)d_in[0];
    const float* kp = (const float*)d_in[1];
    const float* gk = (const float*)d_in[2];
    const int*   pH = (const int*)d_in[3];
    const int*   pW = (const int*)d_in[4];
    float4* out4 = (float4*)d_out;

    const int BN = in_sizes[1] / 2;            // B*N (keypoint_g is B*N*2)
    const int N  = in_sizes[0] / BN;           // Xg is B*N*N

    const int HW4 = (out_size / BN) / 4;       // float4s per plane (host view)
    const int chunks = (HW4 + F4_PER_BLOCK - 1) / F4_PER_BLOCK;

    fused_k<<<dim3(chunks, BN), TPB, 0, stream>>>(Xg, kp, gk, pH, pW, out4, N);
}